// Round 7
// baseline (1567.425 us; speedup 1.0000x reference)
//
#include <hip/hip_runtime.h>
#include <hip/hip_bf16.h>

#define NN 100000
#define NE 3200000
#define NL 1000000
#define NPB 128                         // nodes per bucket (dst >> 7)
#define NB  782                         // ceil(NN / NPB)
#define CAP8 768                        // per-slice per-bucket capacity (mean 512, +11 sigma)

__device__ __forceinline__ long long nt_ll(const void* p) {
    return __builtin_nontemporal_load((const long long*)p);
}

// ---------------- zero int buffer ----------------
__global__ void k_zero(int* __restrict__ p, int n) {
    int i = blockIdx.x * blockDim.x + threadIdx.x;
    if (i < n) p[i] = 0;
}

// ------- bin edges by dst-bucket into per-slice append buffers -------
// slice = blockIdx & 7 (≈ XCD round-robin -> write locality per L2).
// NT loads keep the streaming input from evicting the hot partial write lines.
__global__ void k_bin(const int* __restrict__ src, const int* __restrict__ dst,
                      const float* __restrict__ w, int* __restrict__ cnt8,
                      int2* __restrict__ binned, int e_cnt) {
    int e = blockIdx.x * blockDim.x + threadIdx.x;
    if (e >= e_cnt) return;
    int d = __builtin_nontemporal_load(dst + e);
    int s = __builtin_nontemporal_load(src + e);
    float wv = __builtin_nontemporal_load(w + e);
    int b = d >> 7, dlow = d & 127;
    int x = blockIdx.x & 7;
    int idx = x * NB + b;
    int p = atomicAdd(&cnt8[idx], 1);
    if (p < CAP8) {
        long long ent = (unsigned int)(s | (dlow << 20)) |
                        ((long long)__float_as_int(wv) << 32);
        *(long long*)&binned[(size_t)idx * CAP8 + p] = ent;   // regular store: line should stay
    }
}

// ------- exclusive scan of per-bucket totals -> bucketBase; rowptr[NN]=NE -------
__global__ __launch_bounds__(1024) void k_bases(const int* __restrict__ cnt8,
                                                int* __restrict__ bucketBase,
                                                int* __restrict__ rowptr) {
    __shared__ int part[1024];
    int t = threadIdx.x;
    int T = 0;
    if (t < NB) {
        for (int x = 0; x < 8; ++x) {
            int c = cnt8[x * NB + t];
            T += (c < CAP8 ? c : CAP8);
        }
    }
    part[t] = T;
    __syncthreads();
    for (int off = 1; off < 1024; off <<= 1) {
        int v = (t >= off) ? part[t - off] : 0;
        __syncthreads();
        part[t] += v;
        __syncthreads();
    }
    if (t < NB) bucketBase[t] = part[t] - T;
    if (t == NB - 1) { bucketBase[NB] = part[t]; rowptr[NN] = part[t]; }
}

// ------- per-bucket: LDS counting-sort -> csr (grouped by dst), rowptr, dinv -------
__global__ __launch_bounds__(256) void k_build(const int* __restrict__ cnt8,
                                               const int2* __restrict__ binned,
                                               const int* __restrict__ bucketBase,
                                               int2* __restrict__ csr,
                                               int* __restrict__ rowptr,
                                               float* __restrict__ dinv) {
    __shared__ int2 recs[8 * CAP8];            // 6144 * 8B = 48 KB
    __shared__ int hist[NPB], scn[NPB], cur[NPB], cbase[9];
    __shared__ float degs[NPB];
    int b = blockIdx.x, t = threadIdx.x;
    int node0 = b * NPB;
    int nloc = NN - node0; if (nloc > NPB) nloc = NPB;
    if (t == 0) {
        int s = 0;
        for (int x = 0; x < 8; ++x) {
            cbase[x] = s;
            int c = cnt8[x * NB + b];
            s += (c < CAP8 ? c : CAP8);
        }
        cbase[8] = s;
    }
    if (t < NPB) { hist[t] = 0; degs[t] = 0.0f; }
    __syncthreads();
    for (int x = 0; x < 8; ++x) {
        int n = cbase[x + 1] - cbase[x];
        const int2* sp = binned + (size_t)(x * NB + b) * CAP8;
        for (int i = t; i < n; i += 256) {
            long long v = nt_ll(sp + i);
            int2 r; r.x = (int)v; r.y = (int)(v >> 32);
            recs[cbase[x] + i] = r;
        }
    }
    __syncthreads();
    int T = cbase[8];
    for (int i = t; i < T; i += 256) {
        int2 r = recs[i];
        int dlow = ((unsigned)r.x) >> 20;
        atomicAdd(&hist[dlow], 1);
        atomicAdd(&degs[dlow], __int_as_float(r.y));
    }
    __syncthreads();
    if (t < NPB) scn[t] = hist[t];
    __syncthreads();
    for (int off = 1; off < NPB; off <<= 1) {
        int v = 0;
        if (t < NPB && t >= off) v = scn[t - off];
        __syncthreads();
        if (t < NPB) scn[t] += v;
        __syncthreads();
    }
    int base = bucketBase[b];
    if (t < nloc) {
        int ex = scn[t] - hist[t];
        cur[t] = ex;
        rowptr[node0 + t] = base + ex;
        dinv[node0 + t] = 1.0f / sqrtf(1.0f + degs[t]);   // +1 = self-loop weight
    }
    __syncthreads();
    for (int i = t; i < T; i += 256) {
        int2 r = recs[i];
        int dlow = ((unsigned)r.x) >> 20;
        int slot = atomicAdd(&cur[dlow], 1);
        int2 ent;
        ent.x = r.x & 0xFFFFF;                            // src (raw w stays in .y)
        ent.y = r.y;
        csr[(size_t)base + slot] = ent;                   // scattered only within 48KB window
    }
}

// ---- propagate 32-ch input x (layer-1 reorder), norm folded: 2 nodes/wave ----
__global__ __launch_bounds__(256) void k_prop1x(const float* __restrict__ x,
                                                const int* __restrict__ rowptr,
                                                const int2* __restrict__ csr,
                                                const float* __restrict__ dinv,
                                                float* __restrict__ out, int n) {
    int t = threadIdx.x, wv = t >> 6, lane = t & 63;
    int half = lane >> 5, ch = lane & 31;
    int node = (blockIdx.x * 4 + wv) * 2 + half;
    if (node >= n) return;
    float di = dinv[node];
    float acc = di * di * x[(size_t)node * 32 + ch];
    int lo = rowptr[node], hi = rowptr[node + 1];
    for (int j = lo; j < hi; ++j) {
        long long c = nt_ll(csr + j);
        int s = (int)c;
        float wv_ = __int_as_float((int)(c >> 32));
        float nm = dinv[s] * wv_ * di;
        acc = fmaf(nm, x[(size_t)s * 32 + ch], acc);
    }
    __builtin_nontemporal_store(acc, out + (size_t)node * 32 + ch);
}

// ---------------- GEMM: out[n][64] = h[n][FIN] @ W[FIN][64] (+bias/relu opt) ----
template<int FIN>
__global__ __launch_bounds__(256) void k_gemm(const float* __restrict__ h,
                                              const float* __restrict__ W,
                                              const float* __restrict__ bias,
                                              float* __restrict__ out, int n, int relu) {
    __shared__ float Wl[FIN * 64];
    int t = threadIdx.x;
    for (int i = t; i < FIN * 64; i += 256) Wl[i] = W[i];
    __syncthreads();
    int lane = t & 63, wv = t >> 6;
    float wc[FIN];
#pragma unroll
    for (int k = 0; k < FIN; ++k) wc[k] = Wl[k * 64 + lane];
    float bs = bias ? bias[lane] : 0.0f;
    int base = blockIdx.x * 32 + wv * 8;
#pragma unroll 1
    for (int nd = base; nd < base + 8; ++nd) {
        if (nd >= n) break;
        const float4* row4 = (const float4*)(h + (size_t)nd * FIN);
        float acc = 0.0f;
#pragma unroll
        for (int k4 = 0; k4 < FIN / 4; ++k4) {
            float4 v = row4[k4];
            acc = fmaf(v.x, wc[4 * k4 + 0], acc);
            acc = fmaf(v.y, wc[4 * k4 + 1], acc);
            acc = fmaf(v.z, wc[4 * k4 + 2], acc);
            acc = fmaf(v.w, wc[4 * k4 + 3], acc);
        }
        acc += bs;
        if (relu) acc = fmaxf(acc, 0.0f);
        out[(size_t)nd * 64 + lane] = acc;
    }
}

// -- propagate 64ch, norm folded: out = di^2*hw[n] + sum (dinv[s]*w*di)*hw[s] + b --
__global__ __launch_bounds__(256) void k_prop(const float* __restrict__ hw,
                                              const int* __restrict__ rowptr,
                                              const int2* __restrict__ csr,
                                              const float* __restrict__ dinv,
                                              const float* __restrict__ bias,
                                              float* __restrict__ out, int n, int relu) {
    int t = threadIdx.x;
    int lane = t & 63, wv = t >> 6;
    int node = blockIdx.x * 4 + wv;
    if (node >= n) return;
    float di = dinv[node];
    float acc = di * di * hw[(size_t)node * 64 + lane];
    int lo = rowptr[node], hi = rowptr[node + 1];
    int j = lo;
    for (; j + 3 < hi; j += 4) {               // 4 gathers in flight
        long long c0 = nt_ll(csr + j),     c1 = nt_ll(csr + j + 1);
        long long c2 = nt_ll(csr + j + 2), c3 = nt_ll(csr + j + 3);
        int s0 = (int)c0, s1 = (int)c1, s2 = (int)c2, s3 = (int)c3;
        float g0 = hw[(size_t)s0 * 64 + lane];
        float g1 = hw[(size_t)s1 * 64 + lane];
        float g2 = hw[(size_t)s2 * 64 + lane];
        float g3 = hw[(size_t)s3 * 64 + lane];
        float n0 = dinv[s0] * __int_as_float((int)(c0 >> 32)) * di;
        float n1 = dinv[s1] * __int_as_float((int)(c1 >> 32)) * di;
        float n2 = dinv[s2] * __int_as_float((int)(c2 >> 32)) * di;
        float n3 = dinv[s3] * __int_as_float((int)(c3 >> 32)) * di;
        acc = fmaf(n0, g0, acc);
        acc = fmaf(n1, g1, acc);
        acc = fmaf(n2, g2, acc);
        acc = fmaf(n3, g3, acc);
    }
    for (; j < hi; ++j) {
        long long c = nt_ll(csr + j);
        int s = (int)c;
        float nm = dinv[s] * __int_as_float((int)(c >> 32)) * di;
        acc = fmaf(nm, hw[(size_t)s * 64 + lane], acc);
    }
    acc += bias[lane];
    if (relu) acc = fmaxf(acc, 0.0f);
    __builtin_nontemporal_store(acc, out + (size_t)node * 64 + lane);
}

// ---------------- decoder: out[l] = dot(z[a], z[b]); 16 labels/block ------------
__global__ __launch_bounds__(256) void k_decode(const float* __restrict__ z,
                                                const int* __restrict__ eli,
                                                float* __restrict__ out, int L) {
    __shared__ float res[16];
    int t = threadIdx.x, wv = t >> 6, lane = t & 63;
    int base = blockIdx.x * 16;
#pragma unroll
    for (int k = 0; k < 4; ++k) {
        int l = base + wv * 4 + k;
        float p = 0.0f;
        if (l < L) {
            int a = __builtin_nontemporal_load(eli + l);
            int b = __builtin_nontemporal_load(eli + L + l);
            p = z[(size_t)a * 64 + lane] * z[(size_t)b * 64 + lane];
        }
#pragma unroll
        for (int o = 32; o > 0; o >>= 1) p += __shfl_xor(p, o, 64);
        if (lane == 0) res[wv * 4 + k] = p;
    }
    __syncthreads();
    if (t < 16 && base + t < L) out[base + t] = res[t];
}

extern "C" void kernel_launch(void* const* d_in, const int* in_sizes, int n_in,
                              void* d_out, int out_size, void* d_ws, size_t ws_size,
                              hipStream_t stream) {
    const float* x   = (const float*)d_in[0];        // [NN, 32]
    const float* ew  = (const float*)d_in[1];        // [NE]
    const int*   ei  = (const int*)d_in[2];          // [2, NE]
    const int*   eli = (const int*)d_in[3];          // [2, NL]
    const float* W1 = (const float*)d_in[4];  const float* b1 = (const float*)d_in[5];
    const float* W2 = (const float*)d_in[6];  const float* b2 = (const float*)d_in[7];
    const float* W3 = (const float*)d_in[8];  const float* b3 = (const float*)d_in[9];
    const float* W4 = (const float*)d_in[10]; const float* b4 = (const float*)d_in[11];
    const float* W5 = (const float*)d_in[12]; const float* b5 = (const float*)d_in[13];
    float* out = (float*)d_out;

    const int* src = ei;
    const int* dst = ei + NE;

    // ---- carve workspace (256B aligned) ----
    char* w = (char*)d_ws;
    size_t off = 0;
    auto carve = [&](size_t bytes) -> void* {
        void* p = w + off;
        off = (off + bytes + 255) & ~(size_t)255;
        return p;
    };
    float* dinv     = (float*)carve(sizeof(float) * NN);
    int*   cnt8     = (int*)  carve(sizeof(int) * 8 * NB);
    int*   rowptr   = (int*)  carve(sizeof(int) * (NN + 1));
    int*   bbase    = (int*)  carve(sizeof(int) * (NB + 1));
    int2*  csr      = (int2*) carve(sizeof(int2) * NE);
    // binned (38.4MB) aliases bufA (25.6MB): binned is dead before bufA's
    // first write (k_prop1x runs after k_build's last binned read).
    int2*  binned   = (int2*) carve(sizeof(int2) * (size_t)8 * NB * CAP8);
    float* bufA     = (float*)binned;
    float* bufB     = (float*)carve(sizeof(float) * (size_t)NN * 64);
    (void)ws_size; (void)n_in; (void)in_sizes; (void)out_size;

    const int TB = 256;
    int gE  = (NE + TB - 1) / TB;
    int gW4 = (NN + 3) / 4;       // 4 nodes/block (wave per node)
    int gW8 = (NN + 7) / 8;       // 8 nodes/block (2 per wave, 32ch)
    int gG  = (NN + 31) / 32;     // gemm: 32 nodes/block
    int gD  = (NL + 15) / 16;     // decode: 16 labels/block

    // ---- graph preprocessing: bucketed counting sort -> CSR + dinv ----
    k_zero <<<(8 * NB + TB - 1) / TB, TB, 0, stream>>>(cnt8, 8 * NB);
    k_bin  <<<gE, TB, 0, stream>>>(src, dst, ew, cnt8, binned, NE);
    k_bases<<<1, 1024, 0, stream>>>(cnt8, bbase, rowptr);
    k_build<<<NB, TB, 0, stream>>>(cnt8, binned, bbase, csr, rowptr, dinv);

    // ---- layer 1: (A x) @ W1 + b1, relu ----
    k_prop1x<<<gW8, TB, 0, stream>>>(x, rowptr, csr, dinv, bufA, NN);
    k_gemm<32><<<gG, TB, 0, stream>>>(bufA, W1, b1, bufB, NN, 1);
    // ---- layers 2..4 ----
    k_gemm<64><<<gG, TB, 0, stream>>>(bufB, W2, nullptr, bufA, NN, 0);
    k_prop<<<gW4, TB, 0, stream>>>(bufA, rowptr, csr, dinv, b2, bufB, NN, 1);
    k_gemm<64><<<gG, TB, 0, stream>>>(bufB, W3, nullptr, bufA, NN, 0);
    k_prop<<<gW4, TB, 0, stream>>>(bufA, rowptr, csr, dinv, b3, bufB, NN, 1);
    k_gemm<64><<<gG, TB, 0, stream>>>(bufB, W4, nullptr, bufA, NN, 0);
    k_prop<<<gW4, TB, 0, stream>>>(bufA, rowptr, csr, dinv, b4, bufB, NN, 1);
    // ---- layer 5 (no relu) ----
    k_gemm<64><<<gG, TB, 0, stream>>>(bufB, W5, nullptr, bufA, NN, 0);
    k_prop<<<gW4, TB, 0, stream>>>(bufA, rowptr, csr, dinv, b5, bufB, NN, 0);

    // ---- decode ----
    k_decode<<<gD, TB, 0, stream>>>(bufB, eli, out, NL);
}

// Round 8
// 1327.171 us; speedup vs baseline: 1.1810x; 1.1810x over previous
//
#include <hip/hip_runtime.h>
#include <hip/hip_bf16.h>

#define NN 100000
#define NE 3200000
#define NL 1000000
#define NPB 128                         // nodes per bucket (dst >> 7)
#define NB  782                         // ceil(NN / NPB)
#define CAP8 768                        // per-slice per-bucket capacity (mean 512, +11 sigma)

__device__ __forceinline__ long long nt_ll(const void* p) {
    return __builtin_nontemporal_load((const long long*)p);
}

// ---------------- zero int buffer ----------------
__global__ void k_zero(int* __restrict__ p, int n) {
    int i = blockIdx.x * blockDim.x + threadIdx.x;
    if (i < n) p[i] = 0;
}

// ------- bin edges by dst-bucket into per-slice append buffers -------
// slice = blockIdx & 7 (≈ XCD round-robin -> write locality per L2).
// NT loads OK here: coalesced, each input line touched exactly once.
__global__ void k_bin(const int* __restrict__ src, const int* __restrict__ dst,
                      const float* __restrict__ w, int* __restrict__ cnt8,
                      int2* __restrict__ binned, int e_cnt) {
    int e = blockIdx.x * blockDim.x + threadIdx.x;
    if (e >= e_cnt) return;
    int d = __builtin_nontemporal_load(dst + e);
    int s = __builtin_nontemporal_load(src + e);
    float wv = __builtin_nontemporal_load(w + e);
    int b = d >> 7, dlow = d & 127;
    int x = blockIdx.x & 7;
    int idx = x * NB + b;
    int p = atomicAdd(&cnt8[idx], 1);
    if (p < CAP8) {
        long long ent = (unsigned int)(s | (dlow << 20)) |
                        ((long long)__float_as_int(wv) << 32);
        *(long long*)&binned[(size_t)idx * CAP8 + p] = ent;
    }
}

// ------- exclusive scan of per-bucket totals -> bucketBase; rowptr[NN]=NE -------
__global__ __launch_bounds__(1024) void k_bases(const int* __restrict__ cnt8,
                                                int* __restrict__ bucketBase,
                                                int* __restrict__ rowptr) {
    __shared__ int part[1024];
    int t = threadIdx.x;
    int T = 0;
    if (t < NB) {
        for (int x = 0; x < 8; ++x) {
            int c = cnt8[x * NB + t];
            T += (c < CAP8 ? c : CAP8);
        }
    }
    part[t] = T;
    __syncthreads();
    for (int off = 1; off < 1024; off <<= 1) {
        int v = (t >= off) ? part[t - off] : 0;
        __syncthreads();
        part[t] += v;
        __syncthreads();
    }
    if (t < NB) bucketBase[t] = part[t] - T;
    if (t == NB - 1) { bucketBase[NB] = part[t]; rowptr[NN] = part[t]; }
}

// ------- per-bucket: LDS counting-sort -> csr (grouped by dst), rowptr, dinv -------
__global__ __launch_bounds__(256) void k_build(const int* __restrict__ cnt8,
                                               const int2* __restrict__ binned,
                                               const int* __restrict__ bucketBase,
                                               int2* __restrict__ csr,
                                               int* __restrict__ rowptr,
                                               float* __restrict__ dinv) {
    __shared__ int2 recs[8 * CAP8];            // 6144 * 8B = 48 KB
    __shared__ int hist[NPB], scn[NPB], cur[NPB], cbase[9];
    __shared__ float degs[NPB];
    int b = blockIdx.x, t = threadIdx.x;
    int node0 = b * NPB;
    int nloc = NN - node0; if (nloc > NPB) nloc = NPB;
    if (t == 0) {
        int s = 0;
        for (int x = 0; x < 8; ++x) {
            cbase[x] = s;
            int c = cnt8[x * NB + b];
            s += (c < CAP8 ? c : CAP8);
        }
        cbase[8] = s;
    }
    if (t < NPB) { hist[t] = 0; degs[t] = 0.0f; }
    __syncthreads();
    for (int x = 0; x < 8; ++x) {
        int n = cbase[x + 1] - cbase[x];
        const int2* sp = binned + (size_t)(x * NB + b) * CAP8;
        for (int i = t; i < n; i += 256) {
            long long v = nt_ll(sp + i);       // single-touch stream: NT ok
            int2 r; r.x = (int)v; r.y = (int)(v >> 32);
            recs[cbase[x] + i] = r;
        }
    }
    __syncthreads();
    int T = cbase[8];
    for (int i = t; i < T; i += 256) {
        int2 r = recs[i];
        int dlow = ((unsigned)r.x) >> 20;
        atomicAdd(&hist[dlow], 1);
        atomicAdd(&degs[dlow], __int_as_float(r.y));
    }
    __syncthreads();
    if (t < NPB) scn[t] = hist[t];
    __syncthreads();
    for (int off = 1; off < NPB; off <<= 1) {
        int v = 0;
        if (t < NPB && t >= off) v = scn[t - off];
        __syncthreads();
        if (t < NPB) scn[t] += v;
        __syncthreads();
    }
    int base = bucketBase[b];
    if (t < nloc) {
        int ex = scn[t] - hist[t];
        cur[t] = ex;
        rowptr[node0 + t] = base + ex;
        dinv[node0 + t] = 1.0f / sqrtf(1.0f + degs[t]);   // +1 = self-loop weight
    }
    __syncthreads();
    for (int i = t; i < T; i += 256) {
        int2 r = recs[i];
        int dlow = ((unsigned)r.x) >> 20;
        int slot = atomicAdd(&cur[dlow], 1);
        int2 ent;
        ent.x = r.x & 0xFFFFF;                            // src (raw w stays in .y)
        ent.y = r.y;
        csr[(size_t)base + slot] = ent;                   // scattered only within 48KB window
    }
}

// ---- propagate 32-ch input x, norm folded: wave per node, 2 edges x 32 ch ----
__global__ __launch_bounds__(256) void k_prop1x(const float* __restrict__ x,
                                                const int* __restrict__ rowptr,
                                                const int2* __restrict__ csr,
                                                const float* __restrict__ dinv,
                                                float* __restrict__ out, int n) {
    int t = threadIdx.x, wv = t >> 6, lane = t & 63;
    int ep = lane >> 5, ch = lane & 31;
    int node = blockIdx.x * 4 + wv;
    if (node >= n) return;
    float di = dinv[node];
    int lo = rowptr[node], hi = rowptr[node + 1];
    float acc = 0.0f;
    int j = lo + ep;
    for (; j + 2 < hi; j += 4) {               // 2 edges per half, 2-deep
        int2 e0 = csr[j], e1 = csr[j + 2];
        float g0 = x[(size_t)e0.x * 32 + ch];
        float g1 = x[(size_t)e1.x * 32 + ch];
        float n0 = dinv[e0.x] * __int_as_float(e0.y) * di;
        float n1 = dinv[e1.x] * __int_as_float(e1.y) * di;
        acc = fmaf(n0, g0, acc);
        acc = fmaf(n1, g1, acc);
    }
    if (j < hi) {
        int2 e = csr[j];
        float nm = dinv[e.x] * __int_as_float(e.y) * di;
        acc = fmaf(nm, x[(size_t)e.x * 32 + ch], acc);
    }
    acc += __shfl_xor(acc, 32);                // merge the two edge-halves
    if (ep == 0) {
        acc += di * di * x[(size_t)node * 32 + ch];
        out[(size_t)node * 32 + ch] = acc;
    }
}

// ---------------- GEMM: out[n][64] = h[n][FIN] @ W[FIN][64] (+bias/relu opt) ----
template<int FIN>
__global__ __launch_bounds__(256) void k_gemm(const float* __restrict__ h,
                                              const float* __restrict__ W,
                                              const float* __restrict__ bias,
                                              float* __restrict__ out, int n, int relu) {
    __shared__ float Wl[FIN * 64];
    int t = threadIdx.x;
    for (int i = t; i < FIN * 64; i += 256) Wl[i] = W[i];
    __syncthreads();
    int lane = t & 63, wv = t >> 6;
    float wc[FIN];
#pragma unroll
    for (int k = 0; k < FIN; ++k) wc[k] = Wl[k * 64 + lane];
    float bs = bias ? bias[lane] : 0.0f;
    int base = blockIdx.x * 32 + wv * 8;
#pragma unroll 1
    for (int nd = base; nd < base + 8; ++nd) {
        if (nd >= n) break;
        const float4* row4 = (const float4*)(h + (size_t)nd * FIN);
        float acc = 0.0f;
#pragma unroll
        for (int k4 = 0; k4 < FIN / 4; ++k4) {
            float4 v = row4[k4];
            acc = fmaf(v.x, wc[4 * k4 + 0], acc);
            acc = fmaf(v.y, wc[4 * k4 + 1], acc);
            acc = fmaf(v.z, wc[4 * k4 + 2], acc);
            acc = fmaf(v.w, wc[4 * k4 + 3], acc);
        }
        acc += bs;
        if (relu) acc = fmaxf(acc, 0.0f);
        out[(size_t)nd * 64 + lane] = acc;
    }
}

// -- propagate 64ch, norm folded: out = di^2*hw[n] + sum (dinv[s]*w*di)*hw[s] + b --
__global__ __launch_bounds__(256) void k_prop(const float* __restrict__ hw,
                                              const int* __restrict__ rowptr,
                                              const int2* __restrict__ csr,
                                              const float* __restrict__ dinv,
                                              const float* __restrict__ bias,
                                              float* __restrict__ out, int n, int relu) {
    int t = threadIdx.x;
    int lane = t & 63, wv = t >> 6;
    int node = blockIdx.x * 4 + wv;
    if (node >= n) return;
    float di = dinv[node];
    float acc = di * di * hw[(size_t)node * 64 + lane];
    int lo = rowptr[node], hi = rowptr[node + 1];
    int j = lo;
    for (; j + 3 < hi; j += 4) {               // 4 gathers in flight
        int2 e0 = csr[j],     e1 = csr[j + 1];
        int2 e2 = csr[j + 2], e3 = csr[j + 3];
        float g0 = hw[(size_t)e0.x * 64 + lane];
        float g1 = hw[(size_t)e1.x * 64 + lane];
        float g2 = hw[(size_t)e2.x * 64 + lane];
        float g3 = hw[(size_t)e3.x * 64 + lane];
        float n0 = dinv[e0.x] * __int_as_float(e0.y) * di;
        float n1 = dinv[e1.x] * __int_as_float(e1.y) * di;
        float n2 = dinv[e2.x] * __int_as_float(e2.y) * di;
        float n3 = dinv[e3.x] * __int_as_float(e3.y) * di;
        acc = fmaf(n0, g0, acc);
        acc = fmaf(n1, g1, acc);
        acc = fmaf(n2, g2, acc);
        acc = fmaf(n3, g3, acc);
    }
    for (; j < hi; ++j) {
        int2 e = csr[j];
        float nm = dinv[e.x] * __int_as_float(e.y) * di;
        acc = fmaf(nm, hw[(size_t)e.x * 64 + lane], acc);
    }
    acc += bias[lane];
    if (relu) acc = fmaxf(acc, 0.0f);
    out[(size_t)node * 64 + lane] = acc;
}

// ---------------- decoder: out[l] = dot(z[a], z[b]); 16 labels/block ------------
__global__ __launch_bounds__(256) void k_decode(const float* __restrict__ z,
                                                const int* __restrict__ eli,
                                                float* __restrict__ out, int L) {
    __shared__ float res[16];
    int t = threadIdx.x, wv = t >> 6, lane = t & 63;
    int base = blockIdx.x * 16;
#pragma unroll
    for (int k = 0; k < 4; ++k) {
        int l = base + wv * 4 + k;
        float p = 0.0f;
        if (l < L) {
            int a = __builtin_nontemporal_load(eli + l);
            int b = __builtin_nontemporal_load(eli + L + l);
            p = z[(size_t)a * 64 + lane] * z[(size_t)b * 64 + lane];
        }
#pragma unroll
        for (int o = 32; o > 0; o >>= 1) p += __shfl_xor(p, o, 64);
        if (lane == 0) res[wv * 4 + k] = p;
    }
    __syncthreads();
    if (t < 16 && base + t < L) out[base + t] = res[t];
}

extern "C" void kernel_launch(void* const* d_in, const int* in_sizes, int n_in,
                              void* d_out, int out_size, void* d_ws, size_t ws_size,
                              hipStream_t stream) {
    const float* x   = (const float*)d_in[0];        // [NN, 32]
    const float* ew  = (const float*)d_in[1];        // [NE]
    const int*   ei  = (const int*)d_in[2];          // [2, NE]
    const int*   eli = (const int*)d_in[3];          // [2, NL]
    const float* W1 = (const float*)d_in[4];  const float* b1 = (const float*)d_in[5];
    const float* W2 = (const float*)d_in[6];  const float* b2 = (const float*)d_in[7];
    const float* W3 = (const float*)d_in[8];  const float* b3 = (const float*)d_in[9];
    const float* W4 = (const float*)d_in[10]; const float* b4 = (const float*)d_in[11];
    const float* W5 = (const float*)d_in[12]; const float* b5 = (const float*)d_in[13];
    float* out = (float*)d_out;

    const int* src = ei;
    const int* dst = ei + NE;

    // ---- carve workspace (256B aligned) ----
    char* w = (char*)d_ws;
    size_t off = 0;
    auto carve = [&](size_t bytes) -> void* {
        void* p = w + off;
        off = (off + bytes + 255) & ~(size_t)255;
        return p;
    };
    float* dinv     = (float*)carve(sizeof(float) * NN);
    int*   cnt8     = (int*)  carve(sizeof(int) * 8 * NB);
    int*   rowptr   = (int*)  carve(sizeof(int) * (NN + 1));
    int*   bbase    = (int*)  carve(sizeof(int) * (NB + 1));
    int2*  csr      = (int2*) carve(sizeof(int2) * NE);
    // binned (38.4MB) aliases bufA (25.6MB): binned is dead before bufA's
    // first write (k_prop1x runs after k_build's last binned read).
    int2*  binned   = (int2*) carve(sizeof(int2) * (size_t)8 * NB * CAP8);
    float* bufA     = (float*)binned;
    float* bufB     = (float*)carve(sizeof(float) * (size_t)NN * 64);
    (void)ws_size; (void)n_in; (void)in_sizes; (void)out_size;

    const int TB = 256;
    int gE  = (NE + TB - 1) / TB;
    int gW4 = (NN + 3) / 4;       // 4 nodes/block (wave per node)
    int gG  = (NN + 31) / 32;     // gemm: 32 nodes/block
    int gD  = (NL + 15) / 16;     // decode: 16 labels/block

    // ---- graph preprocessing: bucketed counting sort -> CSR + dinv ----
    k_zero <<<(8 * NB + TB - 1) / TB, TB, 0, stream>>>(cnt8, 8 * NB);
    k_bin  <<<gE, TB, 0, stream>>>(src, dst, ew, cnt8, binned, NE);
    k_bases<<<1, 1024, 0, stream>>>(cnt8, bbase, rowptr);
    k_build<<<NB, TB, 0, stream>>>(cnt8, binned, bbase, csr, rowptr, dinv);

    // ---- layer 1: (A x) @ W1 + b1, relu ----
    k_prop1x<<<gW4, TB, 0, stream>>>(x, rowptr, csr, dinv, bufA, NN);
    k_gemm<32><<<gG, TB, 0, stream>>>(bufA, W1, b1, bufB, NN, 1);
    // ---- layers 2..4 ----
    k_gemm<64><<<gG, TB, 0, stream>>>(bufB, W2, nullptr, bufA, NN, 0);
    k_prop<<<gW4, TB, 0, stream>>>(bufA, rowptr, csr, dinv, b2, bufB, NN, 1);
    k_gemm<64><<<gG, TB, 0, stream>>>(bufB, W3, nullptr, bufA, NN, 0);
    k_prop<<<gW4, TB, 0, stream>>>(bufA, rowptr, csr, dinv, b3, bufB, NN, 1);
    k_gemm<64><<<gG, TB, 0, stream>>>(bufB, W4, nullptr, bufA, NN, 0);
    k_prop<<<gW4, TB, 0, stream>>>(bufA, rowptr, csr, dinv, b4, bufB, NN, 1);
    // ---- layer 5 (no relu) ----
    k_gemm<64><<<gG, TB, 0, stream>>>(bufB, W5, nullptr, bufA, NN, 0);
    k_prop<<<gW4, TB, 0, stream>>>(bufA, rowptr, csr, dinv, b5, bufB, NN, 0);

    // ---- decode ----
    k_decode<<<gD, TB, 0, stream>>>(bufB, eli, out, NL);
}

// Round 9
// 1289.028 us; speedup vs baseline: 1.2160x; 1.0296x over previous
//
#include <hip/hip_runtime.h>
#include <hip/hip_bf16.h>

#define NN 100000
#define NE 3200000
#define NL 1000000
#define NPB 256                         // nodes per bucket (dst >> 8)
#define NB2 391                         // ceil(NN / NPB)
#define CAP 12288                       // per-bucket capacity (mean 8184, +45 sigma)
#define RING 16                         // LDS ring entries per bucket
#define CHUNK 8                         // flush unit: 8 x 8B = 64B = one line

__device__ __forceinline__ long long nt_ll(const void* p) {
    return __builtin_nontemporal_load((const long long*)p);
}

// ---------------- zero int buffer ----------------
__global__ void k_zero(int* __restrict__ p, int n) {
    int i = blockIdx.x * blockDim.x + threadIdx.x;
    if (i < n) p[i] = 0;
}

// ------- LDS-staged binning: edges -> per-bucket streams, full-line flushes -------
__global__ __launch_bounds__(256) void k_bin(const int* __restrict__ src,
                                             const int* __restrict__ dst,
                                             const float* __restrict__ w,
                                             int* __restrict__ gcnt,
                                             long long* __restrict__ binned,
                                             int e_cnt, int epb) {
    __shared__ long long ring[NB2][RING];      // 50048 B
    __shared__ int wcnt[NB2], flu[NB2], bcnt[NB2];
    __shared__ int notdone;
    int t = threadIdx.x;
    for (int i = t; i < NB2; i += 256) { wcnt[i] = 0; flu[i] = 0; bcnt[i] = 0; }
    __syncthreads();

    int e0 = blockIdx.x * epb;
    int nbatch = (epb + 255) >> 8;
    for (int it = 0; it < nbatch; ++it) {
        int off = it * 256 + t;
        int e = e0 + off;
        bool have = (off < epb) && (e < e_cnt);
        long long ent = 0; int b = 0;
        if (have) {
            int d = __builtin_nontemporal_load(dst + e);
            int s = __builtin_nontemporal_load(src + e);
            float wv = __builtin_nontemporal_load(w + e);
            b = d >> 8;
            ent = (unsigned int)(s | ((d & 255) << 17)) |
                  ((long long)__float_as_int(wv) << 32);
        }
        // place/flush rounds until all edges of this batch are staged
        while (true) {
            if (t == 0) notdone = 0;
            __syncthreads();
            int rank = -1;
            if (have) rank = atomicAdd(&bcnt[b], 1);
            __syncthreads();
            if (have) {
                int pend = wcnt[b] - flu[b];
                if (pend + rank < RING) {
                    ring[b][(wcnt[b] + rank) & (RING - 1)] = ent;
                    have = false;
                } else notdone = 1;
            }
            __syncthreads();
            for (int bb = t; bb < NB2; bb += 256) {
                int add = bcnt[bb];
                if (add) {
                    bcnt[bb] = 0;
                    int pend = wcnt[bb] - flu[bb];
                    int room = RING - pend;
                    wcnt[bb] += (add < room) ? add : room;
                    while (wcnt[bb] - flu[bb] >= CHUNK) {
                        int g = atomicAdd(&gcnt[bb], CHUNK);
                        long long* dp = binned + (size_t)bb * CAP + g;
                        int fb = flu[bb] & (RING - 1);
#pragma unroll
                        for (int k = 0; k < CHUNK; ++k)
                            if (g + k < CAP) dp[k] = ring[bb][fb + k];
                        flu[bb] += CHUNK;
                    }
                }
            }
            __syncthreads();
            if (!notdone) break;
        }
    }
    // final drain of partial chunks
    for (int bb = t; bb < NB2; bb += 256) {
        int pend = wcnt[bb] - flu[bb];
        if (pend) {
            int g = atomicAdd(&gcnt[bb], pend);
            long long* dp = binned + (size_t)bb * CAP + g;
            int fb = flu[bb] & (RING - 1);
            for (int k = 0; k < pend; ++k)
                if (g + k < CAP) dp[k] = ring[bb][fb + k];
        }
    }
}

// ------- exclusive scan of per-bucket totals -> bucketBase; rowptr[NN]=total -------
__global__ __launch_bounds__(512) void k_bases(const int* __restrict__ gcnt,
                                               int* __restrict__ bucketBase,
                                               int* __restrict__ rowptr) {
    __shared__ int part[512];
    int t = threadIdx.x;
    int T = 0;
    if (t < NB2) { T = gcnt[t]; if (T > CAP) T = CAP; }
    part[t] = T;
    __syncthreads();
    for (int off = 1; off < 512; off <<= 1) {
        int v = (t >= off) ? part[t - off] : 0;
        __syncthreads();
        part[t] += v;
        __syncthreads();
    }
    if (t < NB2) bucketBase[t] = part[t] - T;
    if (t == NB2 - 1) { bucketBase[NB2] = part[t]; rowptr[NN] = part[t]; }
}

// ------- per-bucket two-pass: hist+deg, scan, scatter -> csr / rowptr / dinv -------
__global__ __launch_bounds__(256) void k_build(const int* __restrict__ gcnt,
                                               const long long* __restrict__ binned,
                                               const int* __restrict__ bucketBase,
                                               int2* __restrict__ csr,
                                               int* __restrict__ rowptr,
                                               float* __restrict__ dinv) {
    __shared__ int hist[NPB], scn[NPB], cur[NPB];
    __shared__ float degs[NPB];
    int b = blockIdx.x, t = threadIdx.x;
    int node0 = b * NPB;
    int nloc = NN - node0; if (nloc > NPB) nloc = NPB;
    hist[t] = 0; degs[t] = 0.0f;
    __syncthreads();
    int T = gcnt[b]; if (T > CAP) T = CAP;
    const long long* bp = binned + (size_t)b * CAP;
    for (int i = t; i < T; i += 256) {
        long long v = bp[i];
        int dlow = ((unsigned)(int)v) >> 17;
        atomicAdd(&hist[dlow], 1);
        atomicAdd(&degs[dlow], __int_as_float((int)(v >> 32)));
    }
    __syncthreads();
    scn[t] = hist[t];
    __syncthreads();
    for (int off = 1; off < NPB; off <<= 1) {
        int v = (t >= off) ? scn[t - off] : 0;
        __syncthreads();
        scn[t] += v;
        __syncthreads();
    }
    int base = bucketBase[b];
    int ex = scn[t] - hist[t];
    cur[t] = ex;
    if (t < nloc) {
        rowptr[node0 + t] = base + ex;
        dinv[node0 + t] = 1.0f / sqrtf(1.0f + degs[t]);   // +1 = self-loop weight
    }
    __syncthreads();
    for (int i = t; i < T; i += 256) {
        long long v = bp[i];
        int xi = (int)v;
        int dlow = ((unsigned)xi) >> 17;
        int slot = atomicAdd(&cur[dlow], 1);
        int2 ent;
        ent.x = xi & 0x1FFFF;
        ent.y = (int)(v >> 32);
        csr[(size_t)base + slot] = ent;        // scatter only within ~100KB window
    }
}

// ---- propagate 32-ch input x, norm folded: wave per node, 2 edges x 32 ch ----
__global__ __launch_bounds__(256) void k_prop1x(const float* __restrict__ x,
                                                const int* __restrict__ rowptr,
                                                const int2* __restrict__ csr,
                                                const float* __restrict__ dinv,
                                                float* __restrict__ out, int n) {
    int t = threadIdx.x, wv = t >> 6, lane = t & 63;
    int ep = lane >> 5, ch = lane & 31;
    int node = blockIdx.x * 4 + wv;
    if (node >= n) return;
    float di = dinv[node];
    int lo = rowptr[node], hi = rowptr[node + 1];
    float acc = 0.0f;
    int j = lo + ep;
    for (; j + 2 < hi; j += 4) {               // 2 edges per half, 2-deep
        int2 e0 = csr[j], e1 = csr[j + 2];
        float g0 = x[(size_t)e0.x * 32 + ch];
        float g1 = x[(size_t)e1.x * 32 + ch];
        float n0 = dinv[e0.x] * __int_as_float(e0.y) * di;
        float n1 = dinv[e1.x] * __int_as_float(e1.y) * di;
        acc = fmaf(n0, g0, acc);
        acc = fmaf(n1, g1, acc);
    }
    if (j < hi) {
        int2 e = csr[j];
        float nm = dinv[e.x] * __int_as_float(e.y) * di;
        acc = fmaf(nm, x[(size_t)e.x * 32 + ch], acc);
    }
    acc += __shfl_xor(acc, 32);                // merge the two edge-halves
    if (ep == 0) {
        acc += di * di * x[(size_t)node * 32 + ch];
        out[(size_t)node * 32 + ch] = acc;
    }
}

// ---------------- GEMM: out[n][64] = h[n][FIN] @ W[FIN][64] (+bias/relu opt) ----
template<int FIN>
__global__ __launch_bounds__(256) void k_gemm(const float* __restrict__ h,
                                              const float* __restrict__ W,
                                              const float* __restrict__ bias,
                                              float* __restrict__ out, int n, int relu) {
    __shared__ float Wl[FIN * 64];
    int t = threadIdx.x;
    for (int i = t; i < FIN * 64; i += 256) Wl[i] = W[i];
    __syncthreads();
    int lane = t & 63, wv = t >> 6;
    float wc[FIN];
#pragma unroll
    for (int k = 0; k < FIN; ++k) wc[k] = Wl[k * 64 + lane];
    float bs = bias ? bias[lane] : 0.0f;
    int base = blockIdx.x * 32 + wv * 8;
#pragma unroll 1
    for (int nd = base; nd < base + 8; ++nd) {
        if (nd >= n) break;
        const float4* row4 = (const float4*)(h + (size_t)nd * FIN);
        float acc = 0.0f;
#pragma unroll
        for (int k4 = 0; k4 < FIN / 4; ++k4) {
            float4 v = row4[k4];
            acc = fmaf(v.x, wc[4 * k4 + 0], acc);
            acc = fmaf(v.y, wc[4 * k4 + 1], acc);
            acc = fmaf(v.z, wc[4 * k4 + 2], acc);
            acc = fmaf(v.w, wc[4 * k4 + 3], acc);
        }
        acc += bs;
        if (relu) acc = fmaxf(acc, 0.0f);
        out[(size_t)nd * 64 + lane] = acc;
    }
}

// -- propagate 64ch, norm folded: out = di^2*hw[n] + sum (dinv[s]*w*di)*hw[s] + b --
__global__ __launch_bounds__(256) void k_prop(const float* __restrict__ hw,
                                              const int* __restrict__ rowptr,
                                              const int2* __restrict__ csr,
                                              const float* __restrict__ dinv,
                                              const float* __restrict__ bias,
                                              float* __restrict__ out, int n, int relu) {
    int t = threadIdx.x;
    int lane = t & 63, wv = t >> 6;
    int node = blockIdx.x * 4 + wv;
    if (node >= n) return;
    float di = dinv[node];
    float acc = di * di * hw[(size_t)node * 64 + lane];
    int lo = rowptr[node], hi = rowptr[node + 1];
    int j = lo;
    for (; j + 3 < hi; j += 4) {               // 4 gathers in flight
        int2 e0 = csr[j],     e1 = csr[j + 1];
        int2 e2 = csr[j + 2], e3 = csr[j + 3];
        float g0 = hw[(size_t)e0.x * 64 + lane];
        float g1 = hw[(size_t)e1.x * 64 + lane];
        float g2 = hw[(size_t)e2.x * 64 + lane];
        float g3 = hw[(size_t)e3.x * 64 + lane];
        float n0 = dinv[e0.x] * __int_as_float(e0.y) * di;
        float n1 = dinv[e1.x] * __int_as_float(e1.y) * di;
        float n2 = dinv[e2.x] * __int_as_float(e2.y) * di;
        float n3 = dinv[e3.x] * __int_as_float(e3.y) * di;
        acc = fmaf(n0, g0, acc);
        acc = fmaf(n1, g1, acc);
        acc = fmaf(n2, g2, acc);
        acc = fmaf(n3, g3, acc);
    }
    for (; j < hi; ++j) {
        int2 e = csr[j];
        float nm = dinv[e.x] * __int_as_float(e.y) * di;
        acc = fmaf(nm, hw[(size_t)e.x * 64 + lane], acc);
    }
    acc += bias[lane];
    if (relu) acc = fmaxf(acc, 0.0f);
    out[(size_t)node * 64 + lane] = acc;
}

// ---------------- decoder: out[l] = dot(z[a], z[b]); 16 labels/block ------------
__global__ __launch_bounds__(256) void k_decode(const float* __restrict__ z,
                                                const int* __restrict__ eli,
                                                float* __restrict__ out, int L) {
    __shared__ float res[16];
    int t = threadIdx.x, wv = t >> 6, lane = t & 63;
    int base = blockIdx.x * 16;
#pragma unroll
    for (int k = 0; k < 4; ++k) {
        int l = base + wv * 4 + k;
        float p = 0.0f;
        if (l < L) {
            int a = __builtin_nontemporal_load(eli + l);
            int b = __builtin_nontemporal_load(eli + L + l);
            p = z[(size_t)a * 64 + lane] * z[(size_t)b * 64 + lane];
        }
#pragma unroll
        for (int o = 32; o > 0; o >>= 1) p += __shfl_xor(p, o, 64);
        if (lane == 0) res[wv * 4 + k] = p;
    }
    __syncthreads();
    if (t < 16 && base + t < L) out[base + t] = res[t];
}

extern "C" void kernel_launch(void* const* d_in, const int* in_sizes, int n_in,
                              void* d_out, int out_size, void* d_ws, size_t ws_size,
                              hipStream_t stream) {
    const float* x   = (const float*)d_in[0];        // [NN, 32]
    const float* ew  = (const float*)d_in[1];        // [NE]
    const int*   ei  = (const int*)d_in[2];          // [2, NE]
    const int*   eli = (const int*)d_in[3];          // [2, NL]
    const float* W1 = (const float*)d_in[4];  const float* b1 = (const float*)d_in[5];
    const float* W2 = (const float*)d_in[6];  const float* b2 = (const float*)d_in[7];
    const float* W3 = (const float*)d_in[8];  const float* b3 = (const float*)d_in[9];
    const float* W4 = (const float*)d_in[10]; const float* b4 = (const float*)d_in[11];
    const float* W5 = (const float*)d_in[12]; const float* b5 = (const float*)d_in[13];
    float* out = (float*)d_out;

    const int* src = ei;
    const int* dst = ei + NE;

    // ---- carve workspace (256B aligned) ----
    char* w = (char*)d_ws;
    size_t off = 0;
    auto carve = [&](size_t bytes) -> void* {
        void* p = w + off;
        off = (off + bytes + 255) & ~(size_t)255;
        return p;
    };
    float*     dinv   = (float*)carve(sizeof(float) * NN);
    int*       gcnt   = (int*)  carve(sizeof(int) * NB2);
    int*       rowptr = (int*)  carve(sizeof(int) * (NN + 1));
    int*       bbase  = (int*)  carve(sizeof(int) * (NB2 + 1));
    int2*      csr    = (int2*) carve(sizeof(int2) * NE);
    // binned (38.4MB) aliases bufA (25.6MB): binned is dead before bufA's
    // first write (k_prop1x runs after k_build's last binned read).
    long long* binned = (long long*)carve(sizeof(long long) * (size_t)NB2 * CAP);
    float*     bufA   = (float*)binned;
    float*     bufB   = (float*)carve(sizeof(float) * (size_t)NN * 64);
    (void)ws_size; (void)n_in; (void)in_sizes; (void)out_size;

    const int TB = 256;
    int gW4 = (NN + 3) / 4;       // 4 nodes/block (wave per node)
    int gG  = (NN + 31) / 32;     // gemm: 32 nodes/block
    int gD  = (NL + 15) / 16;     // decode: 16 labels/block

    // ---- graph preprocessing: LDS-staged partition -> CSR + dinv ----
    const int BINB = 512;
    int epb = (NE + BINB - 1) / BINB;
    k_zero <<<(NB2 + TB - 1) / TB, TB, 0, stream>>>(gcnt, NB2);
    k_bin  <<<BINB, TB, 0, stream>>>(src, dst, ew, gcnt, binned, NE, epb);
    k_bases<<<1, 512, 0, stream>>>(gcnt, bbase, rowptr);
    k_build<<<NB2, TB, 0, stream>>>(gcnt, binned, bbase, csr, rowptr, dinv);

    // ---- layer 1: (A x) @ W1 + b1, relu ----
    k_prop1x<<<gW4, TB, 0, stream>>>(x, rowptr, csr, dinv, bufA, NN);
    k_gemm<32><<<gG, TB, 0, stream>>>(bufA, W1, b1, bufB, NN, 1);
    // ---- layers 2..4 ----
    k_gemm<64><<<gG, TB, 0, stream>>>(bufB, W2, nullptr, bufA, NN, 0);
    k_prop<<<gW4, TB, 0, stream>>>(bufA, rowptr, csr, dinv, b2, bufB, NN, 1);
    k_gemm<64><<<gG, TB, 0, stream>>>(bufB, W3, nullptr, bufA, NN, 0);
    k_prop<<<gW4, TB, 0, stream>>>(bufA, rowptr, csr, dinv, b3, bufB, NN, 1);
    k_gemm<64><<<gG, TB, 0, stream>>>(bufB, W4, nullptr, bufA, NN, 0);
    k_prop<<<gW4, TB, 0, stream>>>(bufA, rowptr, csr, dinv, b4, bufB, NN, 1);
    // ---- layer 5 (no relu) ----
    k_gemm<64><<<gG, TB, 0, stream>>>(bufB, W5, nullptr, bufA, NN, 0);
    k_prop<<<gW4, TB, 0, stream>>>(bufA, rowptr, csr, dinv, b5, bufB, NN, 0);

    // ---- decode ----
    k_decode<<<gD, TB, 0, stream>>>(bufB, eli, out, NL);
}